// Round 4
// baseline (907.451 us; speedup 1.0000x reference)
//
#include <hip/hip_runtime.h>

#define NROWS 262144   // 256*32*32
#define DDIM  64
#define KCODE 1024
#define GATHER_BLOCKS ((NROWS * 16) / 256)   // 16384

// ---- ws layout (bytes) ----
// [0)        eT       float[KCODE*DDIM]  = 262144 B  (codebook transposed, [k][d])
// [262144)   norms    float[KCODE]       = 4096 B    (numpy-sequential-order sum of squares)
// [266240)   idx      int[NROWS]         = 1 MiB
// [1314816)  partials double[16384]      = 128 KiB   (per-block loss partial sums)
//
// SEMANTICS (verified bit-exact, rounds 2-3, absmax 0.0): oracle is numpy fp32
// on an AVX512 host with OpenBLAS sgemm. Replicated rounding:
//   sumx : AVX512 pairwise (4x16-lane accumulate + halving tree)
//   norms: sequential d=0..63 (outer-axis reduce)
//   dot  : sequential FMA d=0..63, single accumulator (sgemm microkernel)
//   dist : fl(fl(sumx+norm) - 2*dot), first-index argmin
//   out  : fl(x + fl(q - x))
// DO NOT change FP op order anywhere in these paths.

// ------------------------------------------------------------------
// P: transpose codebook, numpy-order norms (UNCHANGED, verified)
__global__ __launch_bounds__(256) void vq_prep(const float* __restrict__ e,
                                               float* __restrict__ eT,
                                               float* __restrict__ norms) {
#pragma clang fp contract(off)
    const int k = blockIdx.x * 256 + threadIdx.x;   // 4 blocks x 256 = 1024
    float acc = 0.0f;
    for (int d = 0; d < DDIM; ++d) {
        float v = e[d * KCODE + k];      // e is [D][K]; coalesced across k-lanes
        eT[(k << 6) + d] = v;
        float sq = v * v;                // rounded square (numpy elementwise mul)
        acc = acc + sq;                  // sequential adds (numpy axis-0 reduce)
    }
    norms[k] = acc;
}

// ------------------------------------------------------------------
// numpy AVX512 pairwise sum of fl(x_d^2) — exact op order, do not touch
__device__ __forceinline__ float numpy_sumsq(const float* xr) {
#pragma clang fp contract(off)
    float u[16];
#pragma unroll
    for (int j = 0; j < 16; ++j) {
        float p0 = xr[j     ] * xr[j     ];
        float p1 = xr[j + 16] * xr[j + 16];
        float p2 = xr[j + 32] * xr[j + 32];
        float p3 = xr[j + 48] * xr[j + 48];
        u[j] = (p0 + p1) + (p2 + p3);
    }
    float v8[8];
#pragma unroll
    for (int j = 0; j < 8; ++j) v8[j] = u[j] + u[j + 8];
    float w4[4];
#pragma unroll
    for (int j = 0; j < 4; ++j) w4[j] = v8[j] + v8[j + 4];
    float y0 = w4[0] + w4[2];
    float y1 = w4[1] + w4[3];
    return y0 + y1;
}

// ------------------------------------------------------------------
// 1: per-thread argmin for M=2 rows, bit-exact numpy-fp32 replication.
// __launch_bounds__(256,2): VGPR cap 256 so both 64-float x-rows stay
// register-resident (round 3: default alloc chose 48 VGPRs -> x-row not
// resident -> 3.2x VALU roofline). 8 independent FMA chains per k-quad.
__global__ __launch_bounds__(256, 2) void vq_argmin(const float* __restrict__ x,
                                                    const float* __restrict__ eT,
                                                    const float* __restrict__ norms,
                                                    int* __restrict__ idx) {
#pragma clang fp contract(off)
    const int tid = blockIdx.x * 256 + threadIdx.x;   // 512 blocks
    const int r0  = tid * 2;                          // rows r0, r0+1

    float x0[DDIM], x1[DDIM];
    const float4* xv0 = (const float4*)(x + (size_t)r0 * DDIM);
    const float4* xv1 = (const float4*)(x + (size_t)(r0 + 1) * DDIM);
#pragma unroll
    for (int i = 0; i < DDIM / 4; ++i) {
        float4 a = xv0[i];
        x0[4*i+0] = a.x; x0[4*i+1] = a.y; x0[4*i+2] = a.z; x0[4*i+3] = a.w;
        float4 b = xv1[i];
        x1[4*i+0] = b.x; x1[4*i+1] = b.y; x1[4*i+2] = b.z; x1[4*i+3] = b.w;
    }

    const float sumx0 = numpy_sumsq(x0);
    const float sumx1 = numpy_sumsq(x1);

    float best0 = 3.4e38f, best1 = 3.4e38f;
    int bi0 = 0, bi1 = 0;
    for (int k = 0; k < KCODE; k += 4) {
        // wave-uniform codebook addresses -> scalar (s_load) reads; e-values
        // ride the SGPR operand slot of v_fma (zero extra VALU issue)
        const float* __restrict__ e0 = eT + ((k + 0) << 6);
        const float* __restrict__ e1 = eT + ((k + 1) << 6);
        const float* __restrict__ e2 = eT + ((k + 2) << 6);
        const float* __restrict__ e3 = eT + ((k + 3) << 6);
        float a00 = 0.f, a01 = 0.f, a02 = 0.f, a03 = 0.f;
        float a10 = 0.f, a11 = 0.f, a12 = 0.f, a13 = 0.f;
#pragma unroll
        for (int d = 0; d < DDIM; ++d) {
            float c0 = e0[d], c1 = e1[d], c2 = e2[d], c3 = e3[d];
            a00 = fmaf(x0[d], c0, a00);   // strict sequential d-chain per dot
            a01 = fmaf(x0[d], c1, a01);
            a02 = fmaf(x0[d], c2, a02);
            a03 = fmaf(x0[d], c3, a03);
            a10 = fmaf(x1[d], c0, a10);
            a11 = fmaf(x1[d], c1, a11);
            a12 = fmaf(x1[d], c2, a12);
            a13 = fmaf(x1[d], c3, a13);
        }
        float n0 = norms[k + 0], n1 = norms[k + 1];
        float n2 = norms[k + 2], n3 = norms[k + 3];
        // dist = fl(fl(sumx + norm) - 2*dot); 2*dot exact; first-index argmin
        float d00 = (sumx0 + n0) - 2.0f * a00;
        float d01 = (sumx0 + n1) - 2.0f * a01;
        float d02 = (sumx0 + n2) - 2.0f * a02;
        float d03 = (sumx0 + n3) - 2.0f * a03;
        float d10 = (sumx1 + n0) - 2.0f * a10;
        float d11 = (sumx1 + n1) - 2.0f * a11;
        float d12 = (sumx1 + n2) - 2.0f * a12;
        float d13 = (sumx1 + n3) - 2.0f * a13;
        if (d00 < best0) { best0 = d00; bi0 = k + 0; }
        if (d01 < best0) { best0 = d01; bi0 = k + 1; }
        if (d02 < best0) { best0 = d02; bi0 = k + 2; }
        if (d03 < best0) { best0 = d03; bi0 = k + 3; }
        if (d10 < best1) { best1 = d10; bi1 = k + 0; }
        if (d11 < best1) { best1 = d11; bi1 = k + 1; }
        if (d12 < best1) { best1 = d12; bi1 = k + 2; }
        if (d13 < best1) { best1 = d13; bi1 = k + 3; }
    }
    idx[r0]     = bi0;
    idx[r0 + 1] = bi1;
}

// ------------------------------------------------------------------
// 2: gather + straight-through + per-BLOCK loss partial (UNCHANGED, verified)
__global__ __launch_bounds__(256) void vq_gather(const float* __restrict__ x,
                                                 const float* __restrict__ eT,
                                                 const int* __restrict__ idx,
                                                 float* __restrict__ out,
                                                 double* __restrict__ partials) {
#pragma clang fp contract(off)
    __shared__ float wsum[4];
    const int t   = blockIdx.x * 256 + threadIdx.x;   // NROWS*16 threads
    const int row = t >> 4;
    const int j   = t & 15;
    const int k   = idx[row];
    float4 q  = ((const float4*)eT)[(k << 4) + j];
    float4 xv = ((const float4*)x)[t];
    // numpy: quantized_st = fl(x + fl(q - x))
    float dx = q.x - xv.x, dy = q.y - xv.y, dz = q.z - xv.z, dw = q.w - xv.w;
    float4 o;
    o.x = xv.x + dx; o.y = xv.y + dy; o.z = xv.z + dz; o.w = xv.w + dw;
    ((float4*)out)[t] = o;
    float s = dx*dx + dy*dy + dz*dz + dw*dw;
#pragma unroll
    for (int off = 32; off > 0; off >>= 1) s += __shfl_down(s, off, 64);
    if ((threadIdx.x & 63) == 0) wsum[threadIdx.x >> 6] = s;
    __syncthreads();
    if (threadIdx.x == 0) {
        double b = (double)wsum[0] + (double)wsum[1]
                 + (double)wsum[2] + (double)wsum[3];
        partials[blockIdx.x] = b;
    }
}

// ------------------------------------------------------------------
// 3: reduce block partials; loss = 1.25 * mse (UNCHANGED, verified)
__global__ __launch_bounds__(256) void vq_finalize(const double* __restrict__ partials,
                                                   float* __restrict__ out_loss) {
    __shared__ double sd[256];
    double a = 0.0;
    for (int i = threadIdx.x; i < GATHER_BLOCKS; i += 256) a += partials[i];
    sd[threadIdx.x] = a;
    __syncthreads();
    for (int s = 128; s > 0; s >>= 1) {
        if (threadIdx.x < s) sd[threadIdx.x] += sd[threadIdx.x + s];
        __syncthreads();
    }
    if (threadIdx.x == 0) {
        double mse = sd[0] / (double)((size_t)NROWS * DDIM);
        *out_loss = (float)(1.25 * mse);
    }
}

// ------------------------------------------------------------------
extern "C" void kernel_launch(void* const* d_in, const int* in_sizes, int n_in,
                              void* d_out, int out_size, void* d_ws, size_t ws_size,
                              hipStream_t stream) {
    const float* x = (const float*)d_in[0];        // [N, 64]
    const float* e = (const float*)d_in[1];        // [64, 1024]
    float* out = (float*)d_out;                    // [N*64 quantized_st] + [1 loss]

    char* ws = (char*)d_ws;
    float*  eT       = (float*)(ws + 0);
    float*  norms    = (float*)(ws + 262144);
    int*    idx      = (int*)  (ws + 266240);
    double* partials = (double*)(ws + 1314816);

    vq_prep    <<<KCODE / 256,     256, 0, stream>>>(e, eT, norms);
    vq_argmin  <<<NROWS / 512,     256, 0, stream>>>(x, eT, norms, idx);
    vq_gather  <<<GATHER_BLOCKS,   256, 0, stream>>>(x, eT, idx, out, partials);
    vq_finalize<<<1,               256, 0, stream>>>(partials, out + (size_t)NROWS * DDIM);
}

// Round 5
// 581.051 us; speedup vs baseline: 1.5617x; 1.5617x over previous
//
#include <hip/hip_runtime.h>

#define NROWS 262144   // 256*32*32
#define DDIM  64
#define KCODE 1024
#define GATHER_BLOCKS ((NROWS * 16) / 256)   // 16384
#define WINDOW 4e-3f   // certified: worst-case |approx_s - numpy_s| < 1.6e-3; 2.5x margin

// ---- ws layout (bytes) ----
// [0)        eT       float[KCODE*DDIM]   = 262144 B  (codebook transposed, [k][d])
// [262144)   norms    float[KCODE]        = 4096 B    (numpy-order sum of squares)
// [266240)   eh       ushort[KCODE*DDIM]  = 131072 B  (bf16 hi split of eT)
// [397312)   el       ushort[KCODE*DDIM]  = 131072 B  (bf16 lo split of eT)
// [528384)   idx      int[NROWS]          = 1 MiB     (bit31 = needs exact rescore)
// [1576960)  partials double[16384]       = 128 KiB
//
// SEMANTICS (verified bit-exact rounds 2-4, absmax 0.0): oracle = numpy fp32,
// AVX512 pairwise sumsq, sequential-d fp32-FMA dot, dist = fl(fl(sumx+norm)-2dot),
// first-index argmin, out = fl(x + fl(q-x)). Exact path preserved in vq_prep /
// vq_rescore / vq_gather. vq_filter is an APPROXIMATE pass with a certified
// error window; near-ties are rescored exactly.

typedef short bf16x8 __attribute__((ext_vector_type(8)));
typedef float f32x4  __attribute__((ext_vector_type(4)));

__device__ __forceinline__ unsigned short bf16_rne(float f) {
    unsigned u = __float_as_uint(f);
    unsigned r = u + 0x7fffu + ((u >> 16) & 1u);
    return (unsigned short)(r >> 16);
}

// ------------------------------------------------------------------
// P: transpose codebook, numpy-order norms, bf16 hi/lo splits
__global__ __launch_bounds__(256) void vq_prep(const float* __restrict__ e,
                                               float* __restrict__ eT,
                                               float* __restrict__ norms,
                                               unsigned short* __restrict__ eh,
                                               unsigned short* __restrict__ el) {
#pragma clang fp contract(off)
    const int k = blockIdx.x * 256 + threadIdx.x;   // 4 blocks x 256 = 1024
    float acc = 0.0f;
    for (int d = 0; d < DDIM; ++d) {
        float v = e[d * KCODE + k];      // e is [D][K]; coalesced across k-lanes
        eT[(k << 6) + d] = v;
        unsigned short h = bf16_rne(v);
        float hf = __uint_as_float((unsigned)h << 16);
        eh[(k << 6) + d] = h;
        el[(k << 6) + d] = bf16_rne(v - hf);   // Sterbenz: v-hf exact
        float sq = v * v;                // rounded square (numpy elementwise mul)
        acc = acc + sq;                  // sequential adds (numpy axis-0 reduce)
    }
    norms[k] = acc;
}

// ------------------------------------------------------------------
// numpy AVX512 pairwise sum of fl(x_d^2) — exact op order, do not touch
__device__ __forceinline__ float numpy_sumsq(const float* xr) {
#pragma clang fp contract(off)
    float u[16];
#pragma unroll
    for (int j = 0; j < 16; ++j) {
        float p0 = xr[j     ] * xr[j     ];
        float p1 = xr[j + 16] * xr[j + 16];
        float p2 = xr[j + 32] * xr[j + 32];
        float p3 = xr[j + 48] * xr[j + 48];
        u[j] = (p0 + p1) + (p2 + p3);
    }
    float v8[8];
#pragma unroll
    for (int j = 0; j < 8; ++j) v8[j] = u[j] + u[j + 8];
    float w4[4];
#pragma unroll
    for (int j = 0; j < 4; ++j) w4[j] = v8[j] + v8[j + 4];
    float y0 = w4[0] + w4[2];
    float y1 = w4[1] + w4[3];
    return y0 + y1;
}

// ------------------------------------------------------------------
// 1: MFMA split-bf16 approximate argmin. Wave = 64 rows x 1024 codes.
// s_k = norm_k - 2*dot_k (sumx is row-constant, irrelevant for argmin).
// Flags rows whose top-2 gap <= WINDOW for exact rescore (idx bit 31).
__global__ __launch_bounds__(256, 2) void vq_filter(const float* __restrict__ x,
                                                    const unsigned short* __restrict__ eh,
                                                    const unsigned short* __restrict__ el,
                                                    const float* __restrict__ norms,
                                                    int* __restrict__ idx) {
    const int lane = threadIdx.x & 63;
    const int wave = threadIdx.x >> 6;
    const int wavebase = blockIdx.x * 256 + wave * 64;   // 64 rows per wave
    const int m    = lane & 15;       // A-row within 16 / C-col (code) within 16
    const int quad = lane >> 4;       // k-chunk selector / C-row group

    // ---- build A fragments (hi/lo), 4 row-groups x 2 K-steps ----
    // A layout (verified m120): A[m=lane&15][k=quad*8+j]
    bf16x8 ah[4][2], al[4][2];
#pragma unroll
    for (int g = 0; g < 4; ++g) {
        const float* xp = x + (size_t)(wavebase + g * 16 + m) * DDIM + quad * 8;
#pragma unroll
        for (int s = 0; s < 2; ++s) {
            float4 v0 = *(const float4*)(xp + s * 32);
            float4 v1 = *(const float4*)(xp + s * 32 + 4);
            float f[8] = {v0.x, v0.y, v0.z, v0.w, v1.x, v1.y, v1.z, v1.w};
#pragma unroll
            for (int j = 0; j < 8; ++j) {
                unsigned short h = bf16_rne(f[j]);
                float hf = __uint_as_float((unsigned)h << 16);
                ah[g][s][j] = (short)h;
                al[g][s][j] = (short)bf16_rne(f[j] - hf);
            }
        }
    }

    // ---- per-lane running (min1, min2, argmin) for 4 groups x 4 C-rows ----
    float m1[4][4], m2[4][4];
    int   id[4][4];
#pragma unroll
    for (int g = 0; g < 4; ++g)
#pragma unroll
        for (int r = 0; r < 4; ++r) { m1[g][r] = 3.4e38f; m2[g][r] = 3.4e38f; id[g][r] = 0; }

    for (int tile = 0; tile < KCODE / 16; ++tile) {
        const int code = tile * 16 + m;
        // B layout: eT is B^T ([code][d]); lane loads B^T[n=lane&15][k=quad*8+j]
        const unsigned short* bp_h = eh + (code << 6) + quad * 8;
        const unsigned short* bp_l = el + (code << 6) + quad * 8;
        bf16x8 bh0 = *(const bf16x8*)(bp_h);
        bf16x8 bh1 = *(const bf16x8*)(bp_h + 32);
        bf16x8 bl0 = *(const bf16x8*)(bp_l);
        bf16x8 bl1 = *(const bf16x8*)(bp_l + 32);
        float nrm = norms[code];
#pragma unroll
        for (int g = 0; g < 4; ++g) {
            f32x4 acc = {0.f, 0.f, 0.f, 0.f};
            acc = __builtin_amdgcn_mfma_f32_16x16x32_bf16(ah[g][0], bh0, acc, 0, 0, 0);
            acc = __builtin_amdgcn_mfma_f32_16x16x32_bf16(ah[g][1], bh1, acc, 0, 0, 0);
            acc = __builtin_amdgcn_mfma_f32_16x16x32_bf16(ah[g][0], bl0, acc, 0, 0, 0);
            acc = __builtin_amdgcn_mfma_f32_16x16x32_bf16(ah[g][1], bl1, acc, 0, 0, 0);
            acc = __builtin_amdgcn_mfma_f32_16x16x32_bf16(al[g][0], bh0, acc, 0, 0, 0);
            acc = __builtin_amdgcn_mfma_f32_16x16x32_bf16(al[g][1], bh1, acc, 0, 0, 0);
            // C layout (verified m89/m91): col=lane&15 (code), row=quad*4+reg
#pragma unroll
            for (int r = 0; r < 4; ++r) {
                float sv = fmaf(-2.0f, acc[r], nrm);
                bool lt = sv < m1[g][r];
                m2[g][r] = lt ? m1[g][r] : fminf(m2[g][r], sv);
                m1[g][r] = lt ? sv : m1[g][r];
                id[g][r] = lt ? code : id[g][r];
            }
        }
    }

    // ---- cross-lane merge over the 16 code-columns (lanes sharing quad) ----
#pragma unroll
    for (int g = 0; g < 4; ++g)
#pragma unroll
        for (int r = 0; r < 4; ++r) {
            float a1 = m1[g][r], a2 = m2[g][r];
            int   ai = id[g][r];
            for (int mask = 1; mask < 16; mask <<= 1) {
                float o1 = __shfl_xor(a1, mask, 64);
                float o2 = __shfl_xor(a2, mask, 64);
                int   oi = __shfl_xor(ai, mask, 64);
                float n2 = fminf(fminf(a2, o2), fmaxf(a1, o1));
                bool take = o1 < a1;
                a1 = take ? o1 : a1;
                ai = take ? oi : ai;
                a2 = n2;
            }
            m1[g][r] = a1; m2[g][r] = a2; id[g][r] = ai;
        }

    if (m == 0) {
#pragma unroll
        for (int g = 0; g < 4; ++g)
#pragma unroll
            for (int r = 0; r < 4; ++r) {
                int row = wavebase + g * 16 + quad * 4 + r;
                bool flag = (m2[g][r] - m1[g][r]) <= WINDOW;
                idx[row] = flag ? (id[g][r] | 0x80000000) : id[g][r];
            }
    }
}

// ------------------------------------------------------------------
// R: exact numpy rescore of flagged rows (~4%). One wave per row.
__global__ __launch_bounds__(256) void vq_rescore(const float* __restrict__ x,
                                                  const float* __restrict__ eT,
                                                  const float* __restrict__ norms,
                                                  int* __restrict__ idx) {
#pragma clang fp contract(off)
    const int wave = threadIdx.x >> 6;
    const int lane = threadIdx.x & 63;
    const int rowbase = blockIdx.x * 16 + wave * 4;   // 16384 blocks x 16 rows
    for (int i = 0; i < 4; ++i) {
        const int row = rowbase + i;
        if (idx[row] >= 0) continue;           // uniform branch (broadcast load)
        float xr[DDIM];
        const float4* xv = (const float4*)(x + (size_t)row * DDIM);
#pragma unroll
        for (int t = 0; t < DDIM / 4; ++t) {
            float4 v = xv[t];
            xr[4*t+0] = v.x; xr[4*t+1] = v.y; xr[4*t+2] = v.z; xr[4*t+3] = v.w;
        }
        float sumx = numpy_sumsq(xr);
        float best = 3.4e38f; int bi = 0;
        for (int j = 0; j < 16; ++j) {
            const int k = j * 64 + lane;       // ascending k per lane
            const float* __restrict__ ek = eT + (k << 6);
            float a = 0.f;
#pragma unroll
            for (int d = 0; d < DDIM; ++d)
                a = fmaf(xr[d], ek[d], a);     // strict sequential d-chain
            float t0 = sumx + norms[k];
            float dist = t0 - 2.0f * a;        // fl(fl(sumx+norm) - 2*dot)
            if (dist < best) { best = dist; bi = k; }
        }
        // lexicographic (value, index) min across 64 lanes = first-index argmin
        for (int mask = 32; mask; mask >>= 1) {
            float ov = __shfl_xor(best, mask, 64);
            int   oi = __shfl_xor(bi,   mask, 64);
            if (ov < best || (ov == best && oi < bi)) { best = ov; bi = oi; }
        }
        if (lane == 0) idx[row] = bi;          // clears flag bit
    }
}

// ------------------------------------------------------------------
// 2: gather + straight-through + per-BLOCK loss partial (UNCHANGED, verified)
__global__ __launch_bounds__(256) void vq_gather(const float* __restrict__ x,
                                                 const float* __restrict__ eT,
                                                 const int* __restrict__ idx,
                                                 float* __restrict__ out,
                                                 double* __restrict__ partials) {
#pragma clang fp contract(off)
    __shared__ float wsum[4];
    const int t   = blockIdx.x * 256 + threadIdx.x;   // NROWS*16 threads
    const int row = t >> 4;
    const int j   = t & 15;
    const int k   = idx[row];
    float4 q  = ((const float4*)eT)[(k << 4) + j];
    float4 xv = ((const float4*)x)[t];
    float dx = q.x - xv.x, dy = q.y - xv.y, dz = q.z - xv.z, dw = q.w - xv.w;
    float4 o;
    o.x = xv.x + dx; o.y = xv.y + dy; o.z = xv.z + dz; o.w = xv.w + dw;
    ((float4*)out)[t] = o;
    float s = dx*dx + dy*dy + dz*dz + dw*dw;
#pragma unroll
    for (int off = 32; off > 0; off >>= 1) s += __shfl_down(s, off, 64);
    if ((threadIdx.x & 63) == 0) wsum[threadIdx.x >> 6] = s;
    __syncthreads();
    if (threadIdx.x == 0) {
        double b = (double)wsum[0] + (double)wsum[1]
                 + (double)wsum[2] + (double)wsum[3];
        partials[blockIdx.x] = b;
    }
}

// ------------------------------------------------------------------
// 3: reduce block partials; loss = 1.25 * mse (UNCHANGED, verified)
__global__ __launch_bounds__(256) void vq_finalize(const double* __restrict__ partials,
                                                   float* __restrict__ out_loss) {
    __shared__ double sd[256];
    double a = 0.0;
    for (int i = threadIdx.x; i < GATHER_BLOCKS; i += 256) a += partials[i];
    sd[threadIdx.x] = a;
    __syncthreads();
    for (int s = 128; s > 0; s >>= 1) {
        if (threadIdx.x < s) sd[threadIdx.x] += sd[threadIdx.x + s];
        __syncthreads();
    }
    if (threadIdx.x == 0) {
        double mse = sd[0] / (double)((size_t)NROWS * DDIM);
        *out_loss = (float)(1.25 * mse);
    }
}

// ------------------------------------------------------------------
extern "C" void kernel_launch(void* const* d_in, const int* in_sizes, int n_in,
                              void* d_out, int out_size, void* d_ws, size_t ws_size,
                              hipStream_t stream) {
    const float* x = (const float*)d_in[0];        // [N, 64]
    const float* e = (const float*)d_in[1];        // [64, 1024]
    float* out = (float*)d_out;                    // [N*64 quantized_st] + [1 loss]

    char* ws = (char*)d_ws;
    float*          eT       = (float*)(ws + 0);
    float*          norms    = (float*)(ws + 262144);
    unsigned short* eh       = (unsigned short*)(ws + 266240);
    unsigned short* el       = (unsigned short*)(ws + 397312);
    int*            idx      = (int*)(ws + 528384);
    double*         partials = (double*)(ws + 1576960);

    vq_prep    <<<KCODE / 256,   256, 0, stream>>>(e, eT, norms, eh, el);
    vq_filter  <<<NROWS / 256,   256, 0, stream>>>(x, eh, el, norms, idx);
    vq_rescore <<<NROWS / 16,    256, 0, stream>>>(x, eT, norms, idx);
    vq_gather  <<<GATHER_BLOCKS, 256, 0, stream>>>(x, eT, idx, out, partials);
    vq_finalize<<<1,             256, 0, stream>>>(partials, out + (size_t)NROWS * DDIM);
}